// Round 7
// baseline (178.933 us; speedup 1.0000x reference)
//
#include <hip/hip_runtime.h>
#include <math.h>

#define KK 5
#define C_DIM 256
#define LIN 4096
#define B_DIM 4
#define N_PTS 8192
#define PTS 32
#define WROWS 16
#define WPB (LIN / WROWS)        // 256 windows per batch
#define NWIN (B_DIM * WPB)       // 1024
#define SROWS 28                 // max span rows (16 + 5 + 6 + slack)
#define FS_STRIDE 268
#define H1_STRIDE 76
#define H2_STRIDE 67
#define G_STRIDE 68

typedef short short8 __attribute__((ext_vector_type(8)));
typedef short short4v __attribute__((ext_vector_type(4)));
typedef float f32x4  __attribute__((ext_vector_type(4)));

__device__ __forceinline__ float leaky(float v) { return v >= 0.0f ? v : 0.2f * v; }
__device__ __forceinline__ float softplus_f(float v) { return v > 20.0f ? v : log1pf(expf(v)); }
__device__ __forceinline__ ushort f2bf(float f) {           // RNE f32 -> bf16 bits
    unsigned u = __float_as_uint(f);
    u += 0x7FFFu + ((u >> 16) & 1u);
    return (ushort)(u >> 16);
}
__device__ __forceinline__ float bf2f(ushort h) { return __uint_as_float((unsigned)h << 16); }

__device__ __forceinline__ short8 lds_ld8(const ushort* p) {   // 2 x ds_read_b64
    union { short8 s8; short4v s4[2]; } u;
    u.s4[0] = *(const short4v*)p;
    u.s4[1] = *(const short4v*)(p + 4);
    return u.s8;
}

// ---------------- K0: weight transpose + hi/lo split, and hist zero ---------
__global__ __launch_bounds__(256) void prep_zero(
    const float* __restrict__ W1, const float* __restrict__ Wr,
    ushort* __restrict__ W1t_hi, ushort* __restrict__ W1t_lo,
    ushort* __restrict__ Wrt_hi, ushort* __restrict__ Wrt_lo,
    unsigned* __restrict__ hist)
{
    int blk = blockIdx.x, t = threadIdx.x;
    if (blk == 84) {
        for (int i = t; i < NWIN; i += 256) hist[i] = 0u;
        return;
    }
    int i = blk * 256 + t;
    if (i < 64 * 264) {
        int j = i / 264, k = i % 264;
        float v = (k < 256) ? W1[(size_t)k * 64 + j] : 0.0f;
        ushort hi = f2bf(v);
        W1t_hi[i] = hi;
        W1t_lo[i] = f2bf(v - bf2f(hi));
    } else {
        int i2 = i - 64 * 264;
        if (i2 < 64 * 72) {
            int j = i2 / 72, k = i2 % 72;
            float v = (k < 64) ? Wr[(size_t)k * 64 + j] : 0.0f;
            ushort hi = f2bf(v);
            Wrt_hi[i2] = hi;
            Wrt_lo[i2] = f2bf(v - bf2f(hi));
        }
    }
}

// ---------------- K1: histogram points into (batch, window) buckets ---------
__global__ __launch_bounds__(256) void sort_count(
    const float* __restrict__ coords, unsigned* __restrict__ hist)
{
    int gid = blockIdx.x * 256 + threadIdx.x;   // 8192 threads
#pragma unroll
    for (int i = 0; i < 4; i++) {
        int pt = i * 8192 + gid;
        float x = coords[pt];
        float ix = fminf(fmaxf((x + 1.0f) * 0.5f * (float)(LIN - 1), 0.0f), (float)(LIN - 1));
        int key = (pt >> 13) * WPB + ((int)ix >> 4);
        atomicAdd(&hist[key], 1u);
    }
}

// ---------------- K2: parallel scan (Hillis-Steele) + scatter, one block ----
__global__ __launch_bounds__(256) void scan_scatter(
    const float* __restrict__ coords, const unsigned* __restrict__ hist,
    unsigned* __restrict__ pfx, int* __restrict__ perm)
{
    __shared__ unsigned a[256];
    __shared__ unsigned offs[NWIN];
    int t = threadIdx.x;
    unsigned h0 = hist[4 * t], h1 = hist[4 * t + 1];
    unsigned h2 = hist[4 * t + 2], h3 = hist[4 * t + 3];
    unsigned tsum = h0 + h1 + h2 + h3;
    a[t] = tsum;
    __syncthreads();
    for (int d = 1; d < 256; d <<= 1) {
        unsigned v = (t >= d) ? a[t - d] : 0u;
        __syncthreads();
        a[t] += v;
        __syncthreads();
    }
    unsigned ex = a[t] - tsum;                  // exclusive prefix of this group
    offs[4 * t]     = ex;
    offs[4 * t + 1] = ex + h0;
    offs[4 * t + 2] = ex + h0 + h1;
    offs[4 * t + 3] = ex + h0 + h1 + h2;
    pfx[4 * t]     = offs[4 * t];
    pfx[4 * t + 1] = offs[4 * t + 1];
    pfx[4 * t + 2] = offs[4 * t + 2];
    pfx[4 * t + 3] = offs[4 * t + 3];
    if (t == 255) pfx[NWIN] = a[255];
    __syncthreads();
#pragma unroll 4
    for (int i = 0; i < (B_DIM * N_PTS) / 256; i++) {
        int pt = i * 256 + t;
        float x = coords[pt];
        float ix = fminf(fmaxf((x + 1.0f) * 0.5f * (float)(LIN - 1), 0.0f), (float)(LIN - 1));
        int key = (pt >> 13) * WPB + ((int)ix >> 4);
        unsigned pos = atomicAdd(&offs[key], 1u);
        perm[pos] = pt;
    }
}

// ---------------- K3: fused  stage -> G=F@W1 -> per-point MLP -> gather -----
__global__ __launch_bounds__(256, 3) void fused_kernel(
    const float* __restrict__ feat, const float* __restrict__ coords,
    const float* __restrict__ cell,
    const float* __restrict__ W1, const float* __restrict__ b1,
    const float* __restrict__ br, const float* __restrict__ W3,
    const float* __restrict__ b3,
    const ushort* __restrict__ W1t_hi, const ushort* __restrict__ W1t_lo,
    const ushort* __restrict__ Wrt_hi, const ushort* __restrict__ Wrt_lo,
    const int* __restrict__ perm, const unsigned* __restrict__ pfx,
    float* __restrict__ out)
{
    __shared__ ushort fsh[SROWS * FS_STRIDE];                       // 15008 B
    __shared__ __align__(16) char fslG_raw[SROWS * FS_STRIDE * 2];  // 15008 B union
    ushort* fsl = (ushort*)fslG_raw;          // live during G-pass only
    float*  G   = (float*)fslG_raw;           // [32][68] = 8704 B, live after
    __shared__ ushort H1h[PTS * H1_STRIDE], H1l[PTS * H1_STRIDE];   // 4864 B x2
    __shared__ float  H2[PTS * H2_STRIDE];                          // 8576 B
    __shared__ float  outs[PTS][12];
    __shared__ float  sxw[PTS][10];
    __shared__ float  xs[PTS], cls[PTS], frs[PTS];
    __shared__ int    r0s[PTS], r1s[PTS], pts[PTS];

    const int t = threadIdx.x;
    const int b   = blockIdx.x >> 8;          // NWIN = 4*256
    const int win = blockIdx.x & 255;
    const int w0  = win * WROWS;
    const int rowLo = max(0, w0 - 5);
    const int rowHi = min(LIN, w0 + WROWS + 6);
    const int nrows = rowHi - rowLo;

    // --- stage span rows from [B][C][L], hi/lo split (thread t = channel t) -
    {
        const float* fsrc = feat + ((size_t)b * C_DIM + t) * LIN + rowLo;
#pragma unroll 4
        for (int l = 0; l < nrows; l++) {
            float v = fsrc[l];
            ushort hi = f2bf(v);
            fsh[l * FS_STRIDE + t] = hi;
            fsl[l * FS_STRIDE + t] = f2bf(v - bf2f(hi));
        }
    }
    __syncthreads();

    const int lane = t & 63;
    const int cr = lane & 15, kb = lane >> 4;
    const int jcol = (t >> 6) * 16 + cr;

    // --- G = F_span @ W1 via 3-MFMA hi/lo, 2 M-tiles, accs in regs ----------
    {
        const int rA0 = min(cr, nrows - 1);
        const int rA1 = min(16 + cr, nrows - 1);
        const ushort* B1h = W1t_hi + (size_t)jcol * 264;
        const ushort* B1l = W1t_lo + (size_t)jcol * 264;
        f32x4 g0 = {0.f, 0.f, 0.f, 0.f}, g1 = g0;
#pragma unroll
        for (int k0 = 0; k0 < 256; k0 += 32) {
            int ko = k0 + kb * 8;
            short8 a0h = lds_ld8(fsh + rA0 * FS_STRIDE + ko);
            short8 a0l = lds_ld8(fsl + rA0 * FS_STRIDE + ko);
            short8 a1h = lds_ld8(fsh + rA1 * FS_STRIDE + ko);
            short8 a1l = lds_ld8(fsl + rA1 * FS_STRIDE + ko);
            short8 bh = *(const short8*)(B1h + ko);
            short8 bl = *(const short8*)(B1l + ko);
            g0 = __builtin_amdgcn_mfma_f32_16x16x32_bf16(a0h, bh, g0, 0, 0, 0);
            g0 = __builtin_amdgcn_mfma_f32_16x16x32_bf16(a0h, bl, g0, 0, 0, 0);
            g0 = __builtin_amdgcn_mfma_f32_16x16x32_bf16(a0l, bh, g0, 0, 0, 0);
            g1 = __builtin_amdgcn_mfma_f32_16x16x32_bf16(a1h, bh, g1, 0, 0, 0);
            g1 = __builtin_amdgcn_mfma_f32_16x16x32_bf16(a1h, bl, g1, 0, 0, 0);
            g1 = __builtin_amdgcn_mfma_f32_16x16x32_bf16(a1l, bh, g1, 0, 0, 0);
        }
        __syncthreads();    // all fsl reads complete -> safe to overwrite with G
#pragma unroll
        for (int r = 0; r < 4; r++) {
            G[(kb * 4 + r) * G_STRIDE + jcol]        = g0[r];
            G[(16 + kb * 4 + r) * G_STRIDE + jcol]   = g1[r];
        }
    }

    const unsigned ptStart = pfx[b * WPB + win];
    const unsigned ptEnd   = pfx[b * WPB + win + 1];
    const float brv = br[jcol];

    for (unsigned cb0 = ptStart; cb0 < ptEnd; cb0 += PTS) {
        const int npts = (int)min((unsigned)PTS, ptEnd - cb0);
        __syncthreads();   // G visible (1st iter); prior gather readers done
        if (t < PTS) {
            int pt = perm[cb0 + min(t, npts - 1)];
            pts[t] = pt;
            float x = coords[pt];
            float ix = fminf(fmaxf((x + 1.0f) * 0.5f * (float)(LIN - 1), 0.0f), (float)(LIN - 1));
            float x0f = floorf(ix);
            int i0 = min((int)x0f, LIN - 1);
            int i1 = min(i0 + 1, LIN - 1);
            r0s[t] = i0 - rowLo; r1s[t] = i1 - rowLo;
            frs[t] = ix - x0f; xs[t] = x; cls[t] = cell[pt];
        }
        __syncthreads();

        // --- h1 = leaky(lerp(G) + x*wx + cl*wc + b1), hi/lo into H1 ---------
        {
            int p = t >> 3, j0 = (t & 7) * 8;
            float fr = frs[p], om = 1.0f - fr;
            float xv = xs[p], cv = cls[p];
            const float* g0p = G + r0s[p] * G_STRIDE + j0;
            const float* g1p = G + r1s[p] * G_STRIDE + j0;
            const float* wxp = W1 + (size_t)256 * 64 + j0;
            const float* wcp = W1 + (size_t)257 * 64 + j0;
            const float* b1p = b1 + j0;
            ushort* hh = H1h + p * H1_STRIDE + j0;
            ushort* hl = H1l + p * H1_STRIDE + j0;
#pragma unroll
            for (int e = 0; e < 8; e++) {
                float h = om * g0p[e] + fr * g1p[e] + xv * wxp[e] + cv * wcp[e] + b1p[e];
                h = leaky(h);
                ushort hi = f2bf(h);
                hh[e] = hi;
                hl[e] = f2bf(h - bf2f(hi));
            }
        }
        __syncthreads();

        // --- layer 2 (residual) MFMA ----------------------------------------
        {
            const ushort* B2h = Wrt_hi + (size_t)jcol * 72;
            const ushort* B2l = Wrt_lo + (size_t)jcol * 72;
            f32x4 r0a = {0.f, 0.f, 0.f, 0.f}, r1a = r0a;
#pragma unroll
            for (int k0 = 0; k0 < 64; k0 += 32) {
                int ko = k0 + kb * 8;
                short8 a0h = lds_ld8(H1h + cr * H1_STRIDE + ko);
                short8 a0l = lds_ld8(H1l + cr * H1_STRIDE + ko);
                short8 a1h = lds_ld8(H1h + (16 + cr) * H1_STRIDE + ko);
                short8 a1l = lds_ld8(H1l + (16 + cr) * H1_STRIDE + ko);
                short8 bh = *(const short8*)(B2h + ko);
                short8 bl = *(const short8*)(B2l + ko);
                r0a = __builtin_amdgcn_mfma_f32_16x16x32_bf16(a0h, bh, r0a, 0, 0, 0);
                r0a = __builtin_amdgcn_mfma_f32_16x16x32_bf16(a0h, bl, r0a, 0, 0, 0);
                r0a = __builtin_amdgcn_mfma_f32_16x16x32_bf16(a0l, bh, r0a, 0, 0, 0);
                r1a = __builtin_amdgcn_mfma_f32_16x16x32_bf16(a1h, bh, r1a, 0, 0, 0);
                r1a = __builtin_amdgcn_mfma_f32_16x16x32_bf16(a1h, bl, r1a, 0, 0, 0);
                r1a = __builtin_amdgcn_mfma_f32_16x16x32_bf16(a1l, bh, r1a, 0, 0, 0);
            }
#pragma unroll
            for (int r = 0; r < 4; r++) {
                int p0 = kb * 4 + r;
                float h1v0 = bf2f(H1h[p0 * H1_STRIDE + jcol]) + bf2f(H1l[p0 * H1_STRIDE + jcol]);
                H2[p0 * H2_STRIDE + jcol] = leaky(h1v0 + r0a[r] + brv);
                int p1 = 16 + p0;
                float h1v1 = bf2f(H1h[p1 * H1_STRIDE + jcol]) + bf2f(H1l[p1 * H1_STRIDE + jcol]);
                H2[p1 * H2_STRIDE + jcol] = leaky(h1v1 + r1a[r] + brv);
            }
        }
        __syncthreads();

        // --- layer 3: 12 outputs --------------------------------------------
        {
            int p = t & 31, o = t >> 5;
            for (int oo = o; oo < 12; oo += 8) {
                float acc = b3[oo];
#pragma unroll 8
                for (int l = 0; l < 64; l++)
                    acc = fmaf(H2[p * H2_STRIDE + l], W3[(size_t)l * 12 + oo], acc);
                outs[p][oo] = acc;
            }
        }
        __syncthreads();

        // --- epilogue: sample coords + normalized weights -------------------
        if (t < PTS) {
            float x = xs[t];
            float r = softplus_f(outs[t][0]) + 0.3f;
            r = fminf(fmaxf(r, 0.3f), 2.0f);
            float sg = softplus_f(outs[t][1]) + 0.5f;
            sg = fminf(fmaxf(sg, 0.5f), 3.0f);
            float denom = (sg * 2.0f) * (sg * 2.0f) + 1e-8f;
            const float BASEv[KK] = {-2.0f, -1.0f, 0.0f, 1.0f, 2.0f};
            float wk[KK];
            float wsum = 0.0f;
#pragma unroll
            for (int k = 0; k < KK; k++) {
                float res = tanhf(outs[t][2 + k]) * 0.5f;
                float off = r * BASEv[k] + res;
                float dx = x + off * (2.0f / (float)(LIN - 1));
                float ix = (dx + 1.0f) * 0.5f * (float)(LIN - 1);
                ix = fminf(fmaxf(ix, 0.0f), (float)(LIN - 1));
                float gate = outs[t][2 + KK + k];
                float wgeo = expf(-0.5f * off * off / denom);
                float sig = 1.0f / (1.0f + expf(-gate));
                float w = wgeo * sig;
                sxw[t][k] = ix;
                wk[k] = w; wsum += w;
            }
            float inv = 1.0f / (wsum + 1e-8f);
#pragma unroll
            for (int k = 0; k < KK; k++) sxw[t][5 + k] = wk[k] * inv;
        }
        __syncthreads();

        // --- deformed gather from LDS span, weighted combine, store ---------
        {
            int wg = t >> 5, gl = t & 31;
            int c = gl * 8;
            for (int p = wg; p < npts; p += 8) {
                int pt = pts[p];
                float a0 = 0, a1 = 0, a2 = 0, a3 = 0, a4 = 0, a5 = 0, a6 = 0, a7 = 0;
#pragma unroll
                for (int k = 0; k < KK; k++) {
                    float ix = sxw[p][k];
                    float w  = sxw[p][5 + k];
                    float x0f = floorf(ix);
                    int i0 = (int)x0f;
                    int rr0 = i0 - rowLo;
                    int rr1 = min(i0 + 1, LIN - 1) - rowLo;
                    float fr = ix - x0f;
                    const ushort* q0 = fsh + rr0 * FS_STRIDE + c;
                    const ushort* q1 = fsh + rr1 * FS_STRIDE + c;
                    short4v u0a = *(const short4v*)q0, u0b = *(const short4v*)(q0 + 4);
                    short4v u1a = *(const short4v*)q1, u1b = *(const short4v*)(q1 + 4);
                    float w0f = w * (1.0f - fr), w1f = w * fr;
                    a0 = fmaf(w0f, bf2f((ushort)u0a[0]), fmaf(w1f, bf2f((ushort)u1a[0]), a0));
                    a1 = fmaf(w0f, bf2f((ushort)u0a[1]), fmaf(w1f, bf2f((ushort)u1a[1]), a1));
                    a2 = fmaf(w0f, bf2f((ushort)u0a[2]), fmaf(w1f, bf2f((ushort)u1a[2]), a2));
                    a3 = fmaf(w0f, bf2f((ushort)u0a[3]), fmaf(w1f, bf2f((ushort)u1a[3]), a3));
                    a4 = fmaf(w0f, bf2f((ushort)u0b[0]), fmaf(w1f, bf2f((ushort)u1b[0]), a4));
                    a5 = fmaf(w0f, bf2f((ushort)u0b[1]), fmaf(w1f, bf2f((ushort)u1b[1]), a5));
                    a6 = fmaf(w0f, bf2f((ushort)u0b[2]), fmaf(w1f, bf2f((ushort)u1b[2]), a6));
                    a7 = fmaf(w0f, bf2f((ushort)u0b[3]), fmaf(w1f, bf2f((ushort)u1b[3]), a7));
                }
                float* op = out + (size_t)pt * C_DIM + c;
                *(float4*)op       = make_float4(a0, a1, a2, a3);
                *(float4*)(op + 4) = make_float4(a4, a5, a6, a7);
            }
        }
    }
}

extern "C" void kernel_launch(void* const* d_in, const int* in_sizes, int n_in,
                              void* d_out, int out_size, void* d_ws, size_t ws_size,
                              hipStream_t stream) {
    const float* feat   = (const float*)d_in[0];
    const float* coords = (const float*)d_in[1];
    const float* cell   = (const float*)d_in[2];
    const float* W1 = (const float*)d_in[3];
    const float* b1 = (const float*)d_in[4];
    const float* Wr = (const float*)d_in[5];
    const float* br = (const float*)d_in[6];
    const float* W3 = (const float*)d_in[7];
    const float* b3 = (const float*)d_in[8];
    float* out = (float*)d_out;

    char* ws = (char*)d_ws;
    ushort* W1t_hi = (ushort*)ws; ws += 64 * 264 * 2;
    ushort* W1t_lo = (ushort*)ws; ws += 64 * 264 * 2;
    ushort* Wrt_hi = (ushort*)ws; ws += 64 * 72 * 2;
    ushort* Wrt_lo = (ushort*)ws; ws += 64 * 72 * 2;
    ws = (char*)(((uintptr_t)ws + 255) & ~(uintptr_t)255);
    unsigned* hist = (unsigned*)ws; ws += NWIN * 4;
    unsigned* pfx  = (unsigned*)ws; ws += (NWIN + 1) * 4;
    ws = (char*)(((uintptr_t)ws + 255) & ~(uintptr_t)255);
    int* perm      = (int*)ws;      ws += (size_t)B_DIM * N_PTS * 4;

    prep_zero<<<85, 256, 0, stream>>>(W1, Wr, W1t_hi, W1t_lo, Wrt_hi, Wrt_lo, hist);
    sort_count<<<32, 256, 0, stream>>>(coords, hist);
    scan_scatter<<<1, 256, 0, stream>>>(coords, hist, pfx, perm);
    fused_kernel<<<NWIN, 256, 0, stream>>>(
        feat, coords, cell, W1, b1, br, W3, b3,
        W1t_hi, W1t_lo, Wrt_hi, Wrt_lo, perm, pfx, out);
}